// Round 2
// baseline (203.791 us; speedup 1.0000x reference)
//
#include <hip/hip_runtime.h>
#include <hip/hip_bf16.h>

// Problem constants (from reference): B=1024 batch, L=256 latent, H=512 hidden,
// T=16 node types, N=128 nodes (num_nodes input is a fixed scalar = 128).
#define BB 1024
#define LL 256
#define HH 512
#define TT 16
#define NN 128

#define NODE_F4 (BB * NN * TT / 4)   // 524288 float4
#define EDGE_F4 (BB * NN * NN / 4)   // 4194304 float4

// ---------------------------------------------------------------------------
// K0: W_e1sum[k][j] = W_e1[k][j] + W_e1[k+512][j]   (folds cat(h,h) @ W_e1
// into h @ W_e1sum, halving GEMM2's K). 512*512 floats = 65536 float4.
__global__ __launch_bounds__(256) void k_sumw(const float* __restrict__ We1,
                                              float* __restrict__ Wsum) {
    int q = blockIdx.x * 256 + threadIdx.x;          // 0..65535
    const float4* a = (const float4*)We1;
    float4 t = a[q];
    float4 b = a[q + (HH * HH / 4)];                 // bottom half offset 65536 f4
    float4 r = make_float4(t.x + b.x, t.y + b.y, t.z + b.z, t.w + b.w);
    ((float4*)Wsum)[q] = r;
}

// ---------------------------------------------------------------------------
// Tiled fp32 GEMM + bias + relu:  out[M x HH] = relu(A[M x K] @ W[K x HH] + bias)
//
// R2 redesign for occupancy/latency (R1: 256 blocks = 1/CU, 9.6% occ, 11% VALU):
//   tile = 16 rows x 32 cols, 256 threads, 2 outputs/thread (float2 of cols).
//   grid = (512/32) x (1024/16) = 16 x 64 = 1024 blocks = 4 blocks/CU
//        -> 16 waves/CU (~50% occupancy), 4x the latency hiding of R1.
//   Per wave only 16 distinct W float2 addresses (128B line, broadcast across
//   row-groups) -> 1 L1 line per wave-load. W traffic = 64 row-tiles x 1MB
//   = 64MB, L2-resident.
//   A-tile in LDS, stride padded K+4: ds_read_b128 per 4 k's, 16 distinct
//   row addrs -> 2-way bank aliasing only (free).
template <int K>
__global__ __launch_bounds__(256) void k_gemm_relu(const float* __restrict__ A,
                                                   const float* __restrict__ W,
                                                   const float* __restrict__ bias,
                                                   float* __restrict__ out) {
    constexpr int KP  = K + 4;                       // padded LDS row stride
    constexpr int KF4 = K / 4;                       // float4s per A row
    __shared__ float As[16 * KP];                    // K=512: ~33KB, K=256: ~17KB

    const int tid  = threadIdx.x;
    const int row0 = blockIdx.y * 16;
    const int c2   = tid & 15;                       // column-pair index
    const int col  = blockIdx.x * 32 + c2 * 2;
    const int r    = tid >> 4;                       // 0..15

    // Stage contiguous 16 x K A-tile into padded LDS (float4 chunks).
    const float4* Av = (const float4*)(A + row0 * K);
    #pragma unroll
    for (int q = tid; q < 16 * KF4; q += 256) {
        const int rr = q / KF4;                      // KF4 is pow2 (64 or 128)
        const int kq = q & (KF4 - 1);
        *((float4*)(As + rr * KP + 4 * kq)) = Av[q];
    }
    __syncthreads();

    float accx = 0.f, accy = 0.f;
    const float* Wp = W + col;                       // Wp[k*HH] = W[k][col]
    const float* Ap = As + r * KP;

    #pragma unroll 4
    for (int k4 = 0; k4 < K / 4; ++k4) {
        const int k = k4 * 4;
        float4 a  = *((const float4*)(Ap + k));      // ds_read_b128, 2-way alias
        float2 w0 = *((const float2*)(Wp + (k + 0) * HH));
        float2 w1 = *((const float2*)(Wp + (k + 1) * HH));
        float2 w2 = *((const float2*)(Wp + (k + 2) * HH));
        float2 w3 = *((const float2*)(Wp + (k + 3) * HH));
        accx += a.x * w0.x + a.y * w1.x + a.z * w2.x + a.w * w3.x;
        accy += a.x * w0.y + a.y * w1.y + a.z * w2.y + a.w * w3.y;
    }

    const float2 bb = *((const float2*)(bias + col));
    float* op = out + (row0 + r) * HH + col;
    op[0] = fmaxf(accx + bb.x, 0.f);
    op[1] = fmaxf(accy + bb.y, 0.f);
}

// ---------------------------------------------------------------------------
// K3: per batch row b: node16[b][:] = h[b] @ W_node + b_node  (16 outs, K=512)
//     p[b] = sigmoid(e1[b] @ W_e2 + b_e2)                     (K=512 dot)
// One block (256 threads) per row; 1024 blocks = 4/CU.
__global__ __launch_bounds__(256) void k_head(const float* __restrict__ h,
                                              const float* __restrict__ e1,
                                              const float* __restrict__ Wn,
                                              const float* __restrict__ bn,
                                              const float* __restrict__ We2,
                                              const float* __restrict__ be2,
                                              float* __restrict__ node16,
                                              float* __restrict__ p) {
    const int b   = blockIdx.x;
    const int tid = threadIdx.x;
    __shared__ float hs[HH];
    __shared__ float red[256];

    hs[tid]       = h[b * HH + tid];
    hs[tid + 256] = h[b * HH + tid + 256];
    __syncthreads();

    // node16: 16 outputs x 16 partial-threads each
    const int o = tid & 15, part = tid >> 4;
    float s = 0.f;
    #pragma unroll 4
    for (int kk = 0; kk < 32; ++kk) {
        const int k = part * 32 + kk;
        s += hs[k] * Wn[k * TT + o];
    }
    red[tid] = s;
    __syncthreads();
    if (tid < 16) {
        float t = 0.f;
        #pragma unroll
        for (int q = 0; q < 16; ++q) t += red[q * 16 + tid];
        node16[b * TT + tid] = t + bn[tid];
    }
    __syncthreads();

    // p: 512-dot, 2 elements/thread, wave64 shuffle reduce + cross-wave LDS
    float s2 = e1[b * HH + tid] * We2[tid] + e1[b * HH + tid + 256] * We2[tid + 256];
    #pragma unroll
    for (int off = 32; off; off >>= 1) s2 += __shfl_down(s2, off);
    if ((tid & 63) == 0) red[tid >> 6] = s2;
    __syncthreads();
    if (tid == 0) {
        float t = red[0] + red[1] + red[2] + red[3] + be2[0];
        p[b] = 1.f / (1.f + __expf(-t));
    }
}

// ---------------------------------------------------------------------------
// K4: the 72 MiB broadcast write (the roofline term, ~12-14 us at HBM write BW).
// out layout: [node_logits 1024x128x16][edge_probs 1024x128x128], fp32.
// node_logits[b,n,t] = node16[b][t];  edge_probs[b,i,j] = (j<i) ? p[b] : 0.
__global__ __launch_bounds__(256) void k_write(const float* __restrict__ node16,
                                               const float* __restrict__ p,
                                               float4* __restrict__ out) {
    const int q = blockIdx.x * 256 + threadIdx.x;
    if (q < NODE_F4) {
        const int b  = q >> 9;           // N*T/4 = 512 f4 per batch row
        const int t4 = q & 3;            // 16/4 = 4 f4 per node
        out[q] = ((const float4*)(node16 + b * TT))[t4];
    } else {
        const int e  = q - NODE_F4;
        const int b  = e >> 12;          // N*N/4 = 4096 f4 per batch row
        const int i  = (e >> 5) & 127;   // 128/4 = 32 f4 per i-row
        const int j0 = (e & 31) * 4;
        const float pv = p[b];
        float4 v;
        v.x = (j0 + 0 < i) ? pv : 0.f;
        v.y = (j0 + 1 < i) ? pv : 0.f;
        v.z = (j0 + 2 < i) ? pv : 0.f;
        v.w = (j0 + 3 < i) ? pv : 0.f;
        out[q] = v;
    }
}

// ---------------------------------------------------------------------------
extern "C" void kernel_launch(void* const* d_in, const int* in_sizes, int n_in,
                              void* d_out, int out_size, void* d_ws, size_t ws_size,
                              hipStream_t stream) {
    const float* z    = (const float*)d_in[0];
    // d_in[1] = num_nodes (int scalar) — fixed at 128, hard-coded as NN.
    const float* Wz   = (const float*)d_in[2];
    const float* bz   = (const float*)d_in[3];
    const float* Wn   = (const float*)d_in[4];
    const float* bn   = (const float*)d_in[5];
    const float* We1  = (const float*)d_in[6];
    const float* be1  = (const float*)d_in[7];
    const float* We2  = (const float*)d_in[8];
    const float* be2  = (const float*)d_in[9];
    float* out = (float*)d_out;

    // Workspace layout (floats): h | e1 | W_e1sum | node16 | p   (~5.3 MB)
    float* ws     = (float*)d_ws;
    float* h      = ws;                       // 1024*512
    float* e1     = h + BB * HH;              // 1024*512
    float* Wsum   = e1 + BB * HH;             // 512*512
    float* node16 = Wsum + HH * HH;           // 1024*16
    float* p      = node16 + BB * TT;         // 1024

    // K0: fold W_e1 halves (65536 f4 / 256 threads = 256 blocks)
    k_sumw<<<HH * HH / 4 / 256, 256, 0, stream>>>(We1, Wsum);

    // K1: h = relu(z @ W_z + b_z)   grid: 16 col-tiles x 64 row-tiles
    k_gemm_relu<LL><<<dim3(HH / 32, BB / 16), 256, 0, stream>>>(z, Wz, bz, h);

    // K2: e1 = relu(h @ W_e1sum + b_e1)
    k_gemm_relu<HH><<<dim3(HH / 32, BB / 16), 256, 0, stream>>>(h, Wsum, be1, e1);

    // K3: node16 + p heads
    k_head<<<BB, 256, 0, stream>>>(h, e1, Wn, bn, We2, be2, node16, p);

    // K4: broadcast-write the full output (exactly covers out_size/4 float4s)
    k_write<<<(NODE_F4 + EDGE_F4) / 256, 256, 0, stream>>>(node16, p, (float4*)out);

    (void)in_sizes; (void)n_in; (void)out_size; (void)ws_size;
}

// Round 3
// 130.938 us; speedup vs baseline: 1.5564x; 1.5564x over previous
//
#include <hip/hip_runtime.h>
#include <hip/hip_bf16.h>

// Problem constants: B=1024 batch, L=256 latent, H=512 hidden, T=16 types,
// N=128 nodes (num_nodes input is a fixed scalar = 128).
#define BB 1024
#define LL 256
#define HH 512
#define TT 16
#define NN 128

#define NODE_F4 (BB * NN * TT / 4)   // 524288 float4
#define EDGE_F4 (BB * NN * NN / 4)   // 4194304 float4

typedef short bf16x8 __attribute__((ext_vector_type(8)));   // 8 bf16 = 4 VGPRs
typedef float f32x4  __attribute__((ext_vector_type(4)));   // MFMA C/D

// ---------------------------------------------------------------------------
// P0: elementwise fp32 -> bf16 (for z). One float4 per thread.
__global__ __launch_bounds__(256) void k_conv(const float* __restrict__ in,
                                              __hip_bfloat16* __restrict__ out) {
    const int q = blockIdx.x * 256 + threadIdx.x;
    float4 v = ((const float4*)in)[q];
    out[4 * q + 0] = __float2bfloat16(v.x);
    out[4 * q + 1] = __float2bfloat16(v.y);
    out[4 * q + 2] = __float2bfloat16(v.z);
    out[4 * q + 3] = __float2bfloat16(v.w);
}

// ---------------------------------------------------------------------------
// P1: transpose + convert weights to B^T bf16 layout: out[n][k] = in[k][n].
// FOLD=true additionally adds in[k+HH][n] (folds cat(h,h) @ W_e1 into
// h @ (W_e1_top + W_e1_bot), halving GEMM2's K). 32x32 LDS tile, 256 thr.
template <bool FOLD>
__global__ __launch_bounds__(256) void k_transconv(const float* __restrict__ in,
                                                   __hip_bfloat16* __restrict__ out,
                                                   int Kdim, int Ndim) {
    __shared__ __hip_bfloat16 tile[32][33];
    const int tx = threadIdx.x & 31;
    const int ty = threadIdx.x >> 5;          // 0..7
    const int k0 = blockIdx.y * 32;
    const int n0 = blockIdx.x * 32;
    #pragma unroll
    for (int r = ty; r < 32; r += 8) {
        float v = in[(k0 + r) * Ndim + n0 + tx];
        if (FOLD) v += in[(k0 + r + HH) * Ndim + n0 + tx];
        tile[r][tx] = __float2bfloat16(v);
    }
    __syncthreads();
    #pragma unroll
    for (int r = ty; r < 32; r += 8) {
        out[(n0 + r) * Kdim + k0 + tx] = tile[tx][r];
    }
}

// ---------------------------------------------------------------------------
// G: bf16 MFMA GEMM + bias + relu.  out[M x 512] = relu(A[M x K] @ B + bias),
// B given pre-transposed as Bt[512 x K] bf16.
// One wave per 16x16 output tile: 64 m-tiles x 32 n-tiles = 2048 waves =
// 512 blocks (2 blocks/CU, 8 waves/CU). K-loop fully unrolled:
//   A-frag: lane reads A[mt*16 + (lane&15)][kt*32 + (lane>>4)*8 + 0..7]
//           (16B contiguous, m120-verified A-operand layout)
//   B-frag: lane reads Bt[nt*16 + (lane&15)][same k range]  (m92 B^T layout)
//   C/D:    col = lane&15, row = (lane>>4)*4 + reg          (m89-verified)
template <int K>
__global__ __launch_bounds__(256) void k_mfma_gemm(const __hip_bfloat16* __restrict__ A,
                                                   const __hip_bfloat16* __restrict__ Bt,
                                                   const float* __restrict__ bias,
                                                   __hip_bfloat16* __restrict__ out) {
    const int wid  = (blockIdx.x << 2) + (threadIdx.x >> 6);  // global wave id
    const int lane = threadIdx.x & 63;
    const int mt   = wid >> 5;                 // 0..63  (M/16 = 64)
    const int nt   = wid & 31;                 // 0..31  (512/16 = 32)
    const int l16  = lane & 15;
    const int quad = lane >> 4;

    const short* Ap = (const short*)A  + (mt * 16 + l16) * K + quad * 8;
    const short* Bp = (const short*)Bt + (nt * 16 + l16) * K + quad * 8;

    f32x4 acc = {0.f, 0.f, 0.f, 0.f};
    #pragma unroll
    for (int kt = 0; kt < K / 32; ++kt) {
        bf16x8 a = *(const bf16x8*)(Ap + kt * 32);
        bf16x8 b = *(const bf16x8*)(Bp + kt * 32);
        acc = __builtin_amdgcn_mfma_f32_16x16x32_bf16(a, b, acc, 0, 0, 0);
    }

    const float bb = bias[nt * 16 + l16];
    #pragma unroll
    for (int r = 0; r < 4; ++r) {
        float v = fmaxf(acc[r] + bb, 0.f);
        out[(mt * 16 + quad * 4 + r) * HH + nt * 16 + l16] = __float2bfloat16(v);
    }
}

// ---------------------------------------------------------------------------
// K3: per batch row b: node16[b][:] = h[b] @ W_node + b_node  (16 outs, K=512)
//     p[b] = sigmoid(e1[b] @ W_e2 + b_e2)                     (K=512 dot)
// One block (256 threads) per row. h/e1 are bf16.
__global__ __launch_bounds__(256) void k_head(const __hip_bfloat16* __restrict__ h,
                                              const __hip_bfloat16* __restrict__ e1,
                                              const float* __restrict__ Wn,
                                              const float* __restrict__ bn,
                                              const float* __restrict__ We2,
                                              const float* __restrict__ be2,
                                              float* __restrict__ node16,
                                              float* __restrict__ p) {
    const int b   = blockIdx.x;
    const int tid = threadIdx.x;
    __shared__ float hs[HH];
    __shared__ float red[256];

    hs[tid]       = __bfloat162float(h[b * HH + tid]);
    hs[tid + 256] = __bfloat162float(h[b * HH + tid + 256]);
    __syncthreads();

    // node16: 16 outputs x 16 partial-threads each
    const int o = tid & 15, part = tid >> 4;
    float s = 0.f;
    #pragma unroll 4
    for (int kk = 0; kk < 32; ++kk) {
        const int k = part * 32 + kk;
        s += hs[k] * Wn[k * TT + o];
    }
    red[tid] = s;
    __syncthreads();
    if (tid < 16) {
        float t = 0.f;
        #pragma unroll
        for (int q = 0; q < 16; ++q) t += red[q * 16 + tid];
        node16[b * TT + tid] = t + bn[tid];
    }
    __syncthreads();

    // p: 512-dot, 2 elements/thread, wave64 shuffle reduce + cross-wave LDS
    float s2 = __bfloat162float(e1[b * HH + tid]) * We2[tid]
             + __bfloat162float(e1[b * HH + tid + 256]) * We2[tid + 256];
    #pragma unroll
    for (int off = 32; off; off >>= 1) s2 += __shfl_down(s2, off);
    if ((tid & 63) == 0) red[tid >> 6] = s2;
    __syncthreads();
    if (tid == 0) {
        float t = red[0] + red[1] + red[2] + red[3] + be2[0];
        p[b] = 1.f / (1.f + __expf(-t));
    }
}

// ---------------------------------------------------------------------------
// K4: the 72 MiB broadcast write (the roofline term, ~13 us at HBM write BW).
// out layout: [node_logits 1024x128x16][edge_probs 1024x128x128], fp32.
// node_logits[b,n,t] = node16[b][t];  edge_probs[b,i,j] = (j<i) ? p[b] : 0.
__global__ __launch_bounds__(256) void k_write(const float* __restrict__ node16,
                                               const float* __restrict__ p,
                                               float4* __restrict__ out) {
    const int q = blockIdx.x * 256 + threadIdx.x;
    if (q < NODE_F4) {
        const int b  = q >> 9;           // N*T/4 = 512 f4 per batch row
        const int t4 = q & 3;            // 16/4 = 4 f4 per node
        out[q] = ((const float4*)(node16 + b * TT))[t4];
    } else {
        const int e  = q - NODE_F4;
        const int b  = e >> 12;          // N*N/4 = 4096 f4 per batch row
        const int i  = (e >> 5) & 127;   // 128/4 = 32 f4 per i-row
        const int j0 = (e & 31) * 4;
        const float pv = p[b];
        float4 v;
        v.x = (j0 + 0 < i) ? pv : 0.f;
        v.y = (j0 + 1 < i) ? pv : 0.f;
        v.z = (j0 + 2 < i) ? pv : 0.f;
        v.w = (j0 + 3 < i) ? pv : 0.f;
        out[q] = v;
    }
}

// ---------------------------------------------------------------------------
extern "C" void kernel_launch(void* const* d_in, const int* in_sizes, int n_in,
                              void* d_out, int out_size, void* d_ws, size_t ws_size,
                              hipStream_t stream) {
    const float* z    = (const float*)d_in[0];
    // d_in[1] = num_nodes (int scalar) — fixed at 128, hard-coded as NN.
    const float* Wz   = (const float*)d_in[2];
    const float* bz   = (const float*)d_in[3];
    const float* Wn   = (const float*)d_in[4];
    const float* bn   = (const float*)d_in[5];
    const float* We1  = (const float*)d_in[6];
    const float* be1  = (const float*)d_in[7];
    const float* We2  = (const float*)d_in[8];
    const float* be2  = (const float*)d_in[9];
    float* out = (float*)d_out;

    // Workspace layout (bytes), all 256B-aligned:
    char* base = (char*)d_ws;
    __hip_bfloat16* z_bf  = (__hip_bfloat16*)(base);                 // 512 KB
    __hip_bfloat16* WzT   = (__hip_bfloat16*)(base +  512 * 1024);   // 256 KB [512][256]
    __hip_bfloat16* WsumT = (__hip_bfloat16*)(base +  768 * 1024);   // 512 KB [512][512]
    __hip_bfloat16* h_bf  = (__hip_bfloat16*)(base + 1280 * 1024);   //   1 MB [1024][512]
    __hip_bfloat16* e1_bf = (__hip_bfloat16*)(base + 2304 * 1024);   //   1 MB [1024][512]
    float*          node16 = (float*)(base + 3328 * 1024);           //  64 KB
    float*          p      = (float*)(base + 3392 * 1024);           //   4 KB

    // P0: z -> bf16 (1024*256 = 262144 floats = 65536 float4)
    k_conv<<<BB * LL / 4 / 256, 256, 0, stream>>>(z, z_bf);

    // P1: Wz [256][512] -> WzT [512][256] bf16
    k_transconv<false><<<dim3(HH / 32, LL / 32), 256, 0, stream>>>(Wz, WzT, LL, HH);

    // P2: We1 [1024][512] fold halves -> WsumT [512][512] bf16
    k_transconv<true><<<dim3(HH / 32, HH / 32), 256, 0, stream>>>(We1, WsumT, HH, HH);

    // G1: h = relu(z @ W_z + b_z)      (M=1024, N=512, K=256)
    k_mfma_gemm<LL><<<512, 256, 0, stream>>>(z_bf, WzT, bz, h_bf);

    // G2: e1 = relu(h @ W_e1sum + b_e1)  (M=1024, N=512, K=512)
    k_mfma_gemm<HH><<<512, 256, 0, stream>>>(h_bf, WsumT, be1, e1_bf);

    // K3: node16 + p heads
    k_head<<<BB, 256, 0, stream>>>(h_bf, e1_bf, Wn, bn, We2, be2, node16, p);

    // K4: broadcast-write the full output (exactly covers out_size/4 float4s)
    k_write<<<(NODE_F4 + EDGE_F4) / 256, 256, 0, stream>>>(node16, p, (float4*)out);

    (void)in_sizes; (void)n_in; (void)out_size; (void)ws_size;
}

// Round 4
// 127.413 us; speedup vs baseline: 1.5995x; 1.0277x over previous
//
#include <hip/hip_runtime.h>
#include <hip/hip_bf16.h>
#include <math.h>

// Problem constants: B=1024 batch, L=256 latent, H=512 hidden, T=16 types,
// N=128 nodes (num_nodes input is a fixed scalar = 128).
#define BB 1024
#define LL 256
#define HH 512
#define TT 16
#define NN 128

#define NODE_F4 (BB * NN * TT / 4)   // 524288 float4
#define EDGE_F4 (BB * NN * NN / 4)   // 4194304 float4

typedef short bf16x8 __attribute__((ext_vector_type(8)));   // 8 bf16 = 4 VGPRs
typedef short s16x4  __attribute__((ext_vector_type(4)));   // 4 bf16 = 8 B
typedef float f32x4  __attribute__((ext_vector_type(4)));   // MFMA C/D

static __device__ __forceinline__ short bfbits(float f) {
    __hip_bfloat16 h = __float2bfloat16(f);
    return *reinterpret_cast<short*>(&h);
}

// ---------------------------------------------------------------------------
// K_PREP — fused prologue, one launch, 673 blocks by range:
//   [0,256)   z fp32 -> z_bf bf16 (65536 float4)
//   [256,384) WzT[n][k] = bf16(Wz[k][n])              (512x256, 32x32 tiles)
//   [384,640) WsumT[n][k] = bf16(We1[k][n]+We1[k+512][n])  (512x512 tiles)
//   [640,672) WnT[t][k] = bf16(Wn[k][t])              (16x512, tiny)
//   [672]     p_acc[0..1023] = 0                      (atomic accumulator)
__device__ __forceinline__ void transpose_tile(const float* __restrict__ in,
                                               __hip_bfloat16* __restrict__ out,
                                               int k0, int n0, int Kdim, bool fold,
                                               __hip_bfloat16 (*tile)[34]) {
    const int tx = threadIdx.x & 31;
    const int ty = threadIdx.x >> 5;          // 0..7
    #pragma unroll
    for (int r = ty; r < 32; r += 8) {
        float v = in[(k0 + r) * HH + n0 + tx];        // row stride is 512 both uses
        if (fold) v += in[(k0 + r + HH) * HH + n0 + tx];
        tile[r][tx] = __float2bfloat16(v);
    }
    __syncthreads();
    #pragma unroll
    for (int r = ty; r < 32; r += 8) {
        out[(n0 + r) * Kdim + k0 + tx] = tile[tx][r];
    }
}

__global__ __launch_bounds__(256) void k_prep(const float* __restrict__ z,
                                              const float* __restrict__ Wz,
                                              const float* __restrict__ We1,
                                              const float* __restrict__ Wn,
                                              __hip_bfloat16* __restrict__ z_bf,
                                              __hip_bfloat16* __restrict__ WzT,
                                              __hip_bfloat16* __restrict__ WsumT,
                                              __hip_bfloat16* __restrict__ WnT,
                                              float* __restrict__ p_acc) {
    __shared__ __hip_bfloat16 tile[32][34];   // +2 pad: stride 68B -> conflict-free col reads
    const int bid = blockIdx.x;
    const int tid = threadIdx.x;
    if (bid < 256) {
        const int q = bid * 256 + tid;
        float4 v = ((const float4*)z)[q];
        s16x4 o; o.x = bfbits(v.x); o.y = bfbits(v.y); o.z = bfbits(v.z); o.w = bfbits(v.w);
        ((s16x4*)z_bf)[q] = o;
    } else if (bid < 384) {
        const int t = bid - 256;              // 16 n-tiles x 8 k-tiles
        transpose_tile(Wz, WzT, (t >> 4) * 32, (t & 15) * 32, LL, false, tile);
    } else if (bid < 640) {
        const int t = bid - 384;              // 16 n-tiles x 16 k-tiles
        transpose_tile(We1, WsumT, (t >> 4) * 32, (t & 15) * 32, HH, true, tile);
    } else if (bid < 672) {
        const int u = (bid - 640) * 256 + tid;   // 0..8191
        const int tt = u >> 9, k = u & 511;
        WnT[u] = __float2bfloat16(Wn[k * TT + tt]);
    } else {
        ((float4*)p_acc)[tid] = make_float4(0.f, 0.f, 0.f, 0.f);   // 1024 floats
    }
}

// ---------------------------------------------------------------------------
// G1: h_bf = relu(z_bf @ Wz + bz), M=1024 N=512 K=256, bf16 MFMA.
// One wave per 16x16 tile: 64 mt x 32 nt = 2048 waves = 512 blocks.
// A-frag: A[m=lane&15][k=quad*8+j] (contig 16B); B-frag from B^T likewise;
// C/D: col=lane&15, row=quad*4+reg (m89/m92-verified layouts).
__global__ __launch_bounds__(256) void k_gemm1(const __hip_bfloat16* __restrict__ A,
                                               const __hip_bfloat16* __restrict__ Bt,
                                               const float* __restrict__ bias,
                                               __hip_bfloat16* __restrict__ out) {
    const int wid  = (blockIdx.x << 2) + (threadIdx.x >> 6);
    const int lane = threadIdx.x & 63;
    const int mt = wid >> 5, nt = wid & 31;
    const int l16 = lane & 15, quad = lane >> 4;

    const short* Ap = (const short*)A  + (mt * 16 + l16) * LL + quad * 8;
    const short* Bp = (const short*)Bt + (nt * 16 + l16) * LL + quad * 8;

    f32x4 acc = {0.f, 0.f, 0.f, 0.f};
    #pragma unroll
    for (int kt = 0; kt < LL / 32; ++kt) {
        bf16x8 a = *(const bf16x8*)(Ap + kt * 32);
        bf16x8 b = *(const bf16x8*)(Bp + kt * 32);
        acc = __builtin_amdgcn_mfma_f32_16x16x32_bf16(a, b, acc, 0, 0, 0);
    }
    const int col = nt * 16 + l16;
    const float bb = bias[col];
    #pragma unroll
    for (int r = 0; r < 4; ++r) {
        out[(mt * 16 + quad * 4 + r) * HH + col] = __float2bfloat16(fmaxf(acc[r] + bb, 0.f));
    }
}

// ---------------------------------------------------------------------------
// G2 (fused p-head): per 16x16 tile of e1 = relu(h @ Wsum + be1), multiply by
// We2[col], reduce across the 16 col-lanes (shfl_xor butterfly), atomicAdd
// one partial per row into p_acc[b]. e1 is NEVER materialized.
__global__ __launch_bounds__(256) void k_gemm2_phead(const __hip_bfloat16* __restrict__ A,
                                                     const __hip_bfloat16* __restrict__ Bt,
                                                     const float* __restrict__ be1,
                                                     const float* __restrict__ We2,
                                                     float* __restrict__ p_acc) {
    const int wid  = (blockIdx.x << 2) + (threadIdx.x >> 6);
    const int lane = threadIdx.x & 63;
    const int mt = wid >> 5, nt = wid & 31;
    const int l16 = lane & 15, quad = lane >> 4;

    const short* Ap = (const short*)A  + (mt * 16 + l16) * HH + quad * 8;
    const short* Bp = (const short*)Bt + (nt * 16 + l16) * HH + quad * 8;

    f32x4 acc = {0.f, 0.f, 0.f, 0.f};
    #pragma unroll
    for (int kt = 0; kt < HH / 32; ++kt) {
        bf16x8 a = *(const bf16x8*)(Ap + kt * 32);
        bf16x8 b = *(const bf16x8*)(Bp + kt * 32);
        acc = __builtin_amdgcn_mfma_f32_16x16x32_bf16(a, b, acc, 0, 0, 0);
    }
    const int col = nt * 16 + l16;
    const float bb = be1[col];
    const float w2 = We2[col];
    float sr[4];
    #pragma unroll
    for (int r = 0; r < 4; ++r) sr[r] = fmaxf(acc[r] + bb, 0.f) * w2;
    #pragma unroll
    for (int off = 1; off < 16; off <<= 1) {
        #pragma unroll
        for (int r = 0; r < 4; ++r) sr[r] += __shfl_xor(sr[r], off);
    }
    if (l16 == 0) {
        #pragma unroll
        for (int r = 0; r < 4; ++r)
            atomicAdd(p_acc + mt * 16 + quad * 4 + r, sr[r]);
    }
}

// ---------------------------------------------------------------------------
// K_SMALL: node16 = h @ WnT^T + bn via MFMA (M=1024, N=16, K=512; 64 waves =
// 16 blocks), plus p[b] = sigmoid(p_acc[b] + be2) on the first 1024 threads.
__global__ __launch_bounds__(256) void k_small(const __hip_bfloat16* __restrict__ h,
                                               const __hip_bfloat16* __restrict__ WnT,
                                               const float* __restrict__ bn,
                                               const float* __restrict__ p_acc,
                                               const float* __restrict__ be2,
                                               float* __restrict__ node16,
                                               float* __restrict__ p) {
    const int wid  = (blockIdx.x << 2) + (threadIdx.x >> 6);  // 0..63 = mt
    const int lane = threadIdx.x & 63;
    const int l16 = lane & 15, quad = lane >> 4;

    const short* Ap = (const short*)h   + (wid * 16 + l16) * HH + quad * 8;
    const short* Bp = (const short*)WnT + l16 * HH + quad * 8;

    f32x4 acc = {0.f, 0.f, 0.f, 0.f};
    #pragma unroll
    for (int kt = 0; kt < HH / 32; ++kt) {
        bf16x8 a = *(const bf16x8*)(Ap + kt * 32);
        bf16x8 b = *(const bf16x8*)(Bp + kt * 32);
        acc = __builtin_amdgcn_mfma_f32_16x16x32_bf16(a, b, acc, 0, 0, 0);
    }
    const float bb = bn[l16];
    #pragma unroll
    for (int r = 0; r < 4; ++r)
        node16[(wid * 16 + quad * 4 + r) * TT + l16] = acc[r] + bb;

    const int idx = blockIdx.x * 256 + threadIdx.x;
    if (idx < BB) {
        float t = p_acc[idx] + be2[0];
        p[idx] = 1.f / (1.f + expf(-t));
    }
}

// ---------------------------------------------------------------------------
// K_WRITE: the 72 MiB broadcast write (the true roofline term, ~13 us).
// out = [node_logits 1024x128x16][edge_probs 1024x128x128] fp32.
__global__ __launch_bounds__(256) void k_write(const float* __restrict__ node16,
                                               const float* __restrict__ p,
                                               float4* __restrict__ out) {
    const int q = blockIdx.x * 256 + threadIdx.x;
    if (q < NODE_F4) {
        const int b  = q >> 9;           // N*T/4 = 512 f4 per batch row
        const int t4 = q & 3;
        out[q] = ((const float4*)(node16 + b * TT))[t4];
    } else {
        const int e  = q - NODE_F4;
        const int b  = e >> 12;          // N*N/4 = 4096 f4 per batch row
        const int i  = (e >> 5) & 127;
        const int j0 = (e & 31) * 4;
        const float pv = p[b];
        float4 v;
        v.x = (j0 + 0 < i) ? pv : 0.f;
        v.y = (j0 + 1 < i) ? pv : 0.f;
        v.z = (j0 + 2 < i) ? pv : 0.f;
        v.w = (j0 + 3 < i) ? pv : 0.f;
        out[q] = v;
    }
}

// ---------------------------------------------------------------------------
extern "C" void kernel_launch(void* const* d_in, const int* in_sizes, int n_in,
                              void* d_out, int out_size, void* d_ws, size_t ws_size,
                              hipStream_t stream) {
    const float* z    = (const float*)d_in[0];
    // d_in[1] = num_nodes (int scalar) — fixed at 128, hard-coded as NN.
    const float* Wz   = (const float*)d_in[2];
    const float* bz   = (const float*)d_in[3];
    const float* Wn   = (const float*)d_in[4];
    const float* bn   = (const float*)d_in[5];
    const float* We1  = (const float*)d_in[6];
    const float* be1  = (const float*)d_in[7];
    const float* We2  = (const float*)d_in[8];
    const float* be2  = (const float*)d_in[9];
    float* out = (float*)d_out;

    // Workspace (bytes, 256B-aligned):
    char* base = (char*)d_ws;
    __hip_bfloat16* z_bf   = (__hip_bfloat16*)(base);                 // 512 KB [1024][256]
    __hip_bfloat16* WzT    = (__hip_bfloat16*)(base +  512 * 1024);   // 256 KB [512][256]
    __hip_bfloat16* WsumT  = (__hip_bfloat16*)(base +  768 * 1024);   // 512 KB [512][512]
    __hip_bfloat16* WnT    = (__hip_bfloat16*)(base + 1280 * 1024);   //  16 KB [16][512]
    __hip_bfloat16* h_bf   = (__hip_bfloat16*)(base + 1296 * 1024);   //   1 MB [1024][512]
    float*          node16 = (float*)(base + 2320 * 1024);            //  64 KB [1024][16]
    float*          p_acc  = (float*)(base + 2384 * 1024);            //   4 KB
    float*          p      = (float*)(base + 2388 * 1024);            //   4 KB

    // 1) fused prologue (convert + transposes + p_acc zero)
    k_prep<<<673, 256, 0, stream>>>(z, Wz, We1, Wn, z_bf, WzT, WsumT, WnT, p_acc);

    // 2) h = relu(z @ Wz + bz)   (M=1024, K=256)
    k_gemm1<<<512, 256, 0, stream>>>(z_bf, WzT, bz, h_bf);

    // 3) fused e1-GEMM + We2 dot -> p_acc  (e1 never stored)
    k_gemm2_phead<<<512, 256, 0, stream>>>(h_bf, WsumT, be1, We2, p_acc);

    // 4) node16 MFMA + sigmoid finalize
    k_small<<<16, 256, 0, stream>>>(h_bf, WnT, bn, p_acc, be2, node16, p);

    // 5) 72 MiB broadcast write
    k_write<<<(NODE_F4 + EDGE_F4) / 256, 256, 0, stream>>>(node16, p, (float4*)out);

    (void)in_sizes; (void)n_in; (void)out_size; (void)ws_size;
}